// Round 1
// baseline (584.035 us; speedup 1.0000x reference)
//
#include <hip/hip_runtime.h>

// ComplexMultiHeadAttention: B=2, N=2048, D=1024, H=16, hd=64
// Pipeline: [qkv_gemm r/i] -> ws(q,k,vT bf16) -> [flash attn complex] -> ws(o bf16) -> [out_gemm r/i] -> d_out f32
// ws usage: 4 * 8388608 bf16 elems = 67.1 MB

#define DIM_   1024
#define HEADS_ 16
#define HD_    64
#define BB_    2
#define NN_    2048
#define MTOT_  (BB_*NN_)      // 4096
#define SCALE_ 0.125f

typedef __bf16 bf16;
typedef __bf16 bf16x8 __attribute__((ext_vector_type(8)));
typedef short  s16x8  __attribute__((ext_vector_type(8)));
typedef float  fx4    __attribute__((ext_vector_type(4)));

__device__ __forceinline__ bf16x8 neg8(bf16x8 v) {
    s16x8 s;
    __builtin_memcpy(&s, &v, sizeof(s));
    s ^= (short)0x8000;
    bf16x8 r;
    __builtin_memcpy(&r, &s, sizeof(r));
    return r;
}

// ---------------------------------------------------------------------------
// QKV GEMM: C[m,c] = x[m,:] . Wqkv[c,:] + b[c];  M=4096, C=3072, K=1024
// blockIdx.z: 0=real, 1=imag. Epilogue scatters into per-head q/k/vT (bf16).
// 128x128 tile, BK=32, 256 threads (4 waves, each 64x64 = 4x4 MFMA blocks).
// ---------------------------------------------------------------------------
__global__ __launch_bounds__(256) void qkv_gemm(
    const float* __restrict__ xr, const float* __restrict__ xi,
    const float* __restrict__ Wr, const float* __restrict__ Wi,
    const float* __restrict__ br, const float* __restrict__ bi,
    bf16* __restrict__ qbuf, bf16* __restrict__ kbuf, bf16* __restrict__ vbuf)
{
    const int z = blockIdx.z;
    const float* __restrict__ A    = z ? xi : xr;
    const float* __restrict__ W    = z ? Wi : Wr;
    const float* __restrict__ bias = z ? bi : br;
    const int n0 = blockIdx.x * 128;
    const int m0 = blockIdx.y * 128;

    __shared__ bf16 As[128*40];   // stride 40 (pad 8) to break bank strides
    __shared__ bf16 Bs[128*40];

    const int tid  = threadIdx.x;
    const int w    = tid >> 6, lane = tid & 63;
    const int quad = lane >> 4, lc = lane & 15;
    const int wm   = (w >> 1) * 64, wn = (w & 1) * 64;

    const fx4 fzero = {0.f, 0.f, 0.f, 0.f};
    fx4 acc[4][4];
#pragma unroll
    for (int mi = 0; mi < 4; ++mi)
#pragma unroll
        for (int ni = 0; ni < 4; ++ni) acc[mi][ni] = fzero;

    for (int k0 = 0; k0 < DIM_; k0 += 32) {
#pragma unroll
        for (int it = 0; it < 2; ++it) {
            int flat = it*2048 + tid*8;          // 128x32 f32 tile, 8 f32/thread/iter
            int row = flat >> 5, col = flat & 31;
            const float* pa = A + (size_t)(m0+row)*DIM_ + k0 + col;
            const float* pb = W + (size_t)(n0+row)*DIM_ + k0 + col;
            fx4 a0 = *(const fx4*)pa, a1 = *(const fx4*)(pa+4);
            fx4 b0 = *(const fx4*)pb, b1 = *(const fx4*)(pb+4);
            bf16x8 av, bv;
#pragma unroll
            for (int j = 0; j < 4; ++j) {
                av[j] = (bf16)a0[j]; av[j+4] = (bf16)a1[j];
                bv[j] = (bf16)b0[j]; bv[j+4] = (bf16)b1[j];
            }
            *(bf16x8*)&As[row*40 + col] = av;
            *(bf16x8*)&Bs[row*40 + col] = bv;
        }
        __syncthreads();

        bf16x8 af[4], bfr[4];
#pragma unroll
        for (int mi = 0; mi < 4; ++mi) af[mi]  = *(bf16x8*)&As[(wm + mi*16 + lc)*40 + quad*8];
#pragma unroll
        for (int ni = 0; ni < 4; ++ni) bfr[ni] = *(bf16x8*)&Bs[(wn + ni*16 + lc)*40 + quad*8];
#pragma unroll
        for (int mi = 0; mi < 4; ++mi)
#pragma unroll
            for (int ni = 0; ni < 4; ++ni)
                acc[mi][ni] = __builtin_amdgcn_mfma_f32_16x16x32_bf16(af[mi], bfr[ni], acc[mi][ni], 0, 0, 0);
        __syncthreads();
    }

    // Epilogue: bias + bf16 + scatter.  c: [0,1024)=q, [1024,2048)=k, [2048,3072)=v(T)
#pragma unroll
    for (int mi = 0; mi < 4; ++mi)
#pragma unroll
        for (int ni = 0; ni < 4; ++ni)
#pragma unroll
            for (int r = 0; r < 4; ++r) {
                int gm = m0 + wm + mi*16 + quad*4 + r;
                int gc = n0 + wn + ni*16 + lc;
                float val = acc[mi][ni][r] + bias[gc];
                bf16 bv = (bf16)val;
                int which = gc >> 10, h = (gc >> 6) & 15, hd = gc & 63;
                int b = gm >> 11, n = gm & 2047;
                size_t base = (size_t)((z*BB_ + b)*HEADS_ + h);
                if (which == 0)      qbuf[(base*NN_ + n)*HD_ + hd] = bv;
                else if (which == 1) kbuf[(base*NN_ + n)*HD_ + hd] = bv;
                else                 vbuf[(base*HD_ + hd)*NN_ + n] = bv;   // V transposed
            }
}

// ---------------------------------------------------------------------------
// Flash attention with complex magnitude scores.
// grid (N/64, H, B), 256 threads. Each wave owns a 16-row Q band.
// S_r = qr.kr + qi.ki ; S_i = qi.kr - qr.ki ; mag = SCALE*sqrt(Sr^2+Si^2)
// Online softmax over key tiles of 64; P round-trips LDS (C-layout -> A-layout).
// ---------------------------------------------------------------------------
__global__ __launch_bounds__(256) void attn_fwd(
    const bf16* __restrict__ qbuf, const bf16* __restrict__ kbuf,
    const bf16* __restrict__ vbuf, bf16* __restrict__ obuf)
{
    const int q0 = blockIdx.x * 64;
    const int h  = blockIdx.y;
    const int b  = blockIdx.z;
    const int tid  = threadIdx.x;
    const int w    = tid >> 6, lane = tid & 63;
    const int quad = lane >> 4, lc = lane & 15;

    __shared__ bf16 Qr[64*72], Qi[64*72];
    __shared__ bf16 Kr[64*72], Ki[64*72];
    __shared__ bf16 Vr[64*72], Vi[64*72];   // transposed V tiles: [hd][key]
    __shared__ bf16 Ps[64*72];

    const size_t hR = (size_t)(0*BB_ + b)*HEADS_ + h;
    const size_t hI = (size_t)(1*BB_ + b)*HEADS_ + h;
    const bf16* qrg = qbuf + hR*NN_*HD_;
    const bf16* qig = qbuf + hI*NN_*HD_;
    const bf16* krg = kbuf + hR*NN_*HD_;
    const bf16* kig = kbuf + hI*NN_*HD_;
    const bf16* vrg = vbuf + hR*HD_*NN_;
    const bf16* vig = vbuf + hI*HD_*NN_;

    // stage Q tiles (64 rows x 64 d)
#pragma unroll
    for (int it = 0; it < 2; ++it) {
        int flat = it*2048 + tid*8;
        int row = flat >> 6, col = flat & 63;
        *(bf16x8*)&Qr[row*72 + col] = *(const bf16x8*)&qrg[(size_t)(q0+row)*HD_ + col];
        *(bf16x8*)&Qi[row*72 + col] = *(const bf16x8*)&qig[(size_t)(q0+row)*HD_ + col];
    }
    __syncthreads();

    const int frow = (w*16 + lc)*72;
    bf16x8 qr0 = *(bf16x8*)&Qr[frow + quad*8];
    bf16x8 qr1 = *(bf16x8*)&Qr[frow + 32 + quad*8];
    bf16x8 qi0 = *(bf16x8*)&Qi[frow + quad*8];
    bf16x8 qi1 = *(bf16x8*)&Qi[frow + 32 + quad*8];
    bf16x8 nqr0 = neg8(qr0), nqr1 = neg8(qr1);

    const fx4 fzero = {0.f, 0.f, 0.f, 0.f};
    float m_[4], l_[4];
#pragma unroll
    for (int r = 0; r < 4; ++r) { m_[r] = -1e30f; l_[r] = 0.f; }
    fx4 Or[4], Oi[4];
#pragma unroll
    for (int nb = 0; nb < 4; ++nb) { Or[nb] = fzero; Oi[nb] = fzero; }

    for (int n0 = 0; n0 < NN_; n0 += 64) {
#pragma unroll
        for (int it = 0; it < 2; ++it) {
            int flat = it*2048 + tid*8;
            int row = flat >> 6, col = flat & 63;
            *(bf16x8*)&Kr[row*72 + col] = *(const bf16x8*)&krg[(size_t)(n0+row)*HD_ + col];
            *(bf16x8*)&Ki[row*72 + col] = *(const bf16x8*)&kig[(size_t)(n0+row)*HD_ + col];
            *(bf16x8*)&Vr[row*72 + col] = *(const bf16x8*)&vrg[(size_t)row*NN_ + n0 + col];
            *(bf16x8*)&Vi[row*72 + col] = *(const bf16x8*)&vig[(size_t)row*NN_ + n0 + col];
        }
        __syncthreads();

        fx4 Sr[4], Si[4];
#pragma unroll
        for (int nb = 0; nb < 4; ++nb) {
            int krow = (nb*16 + lc)*72;
            bf16x8 kr0f = *(bf16x8*)&Kr[krow + quad*8];
            bf16x8 kr1f = *(bf16x8*)&Kr[krow + 32 + quad*8];
            bf16x8 ki0f = *(bf16x8*)&Ki[krow + quad*8];
            bf16x8 ki1f = *(bf16x8*)&Ki[krow + 32 + quad*8];
            fx4 sr = fzero, si = fzero;
            sr = __builtin_amdgcn_mfma_f32_16x16x32_bf16(qr0,  kr0f, sr, 0,0,0);
            sr = __builtin_amdgcn_mfma_f32_16x16x32_bf16(qr1,  kr1f, sr, 0,0,0);
            sr = __builtin_amdgcn_mfma_f32_16x16x32_bf16(qi0,  ki0f, sr, 0,0,0);
            sr = __builtin_amdgcn_mfma_f32_16x16x32_bf16(qi1,  ki1f, sr, 0,0,0);
            si = __builtin_amdgcn_mfma_f32_16x16x32_bf16(qi0,  kr0f, si, 0,0,0);
            si = __builtin_amdgcn_mfma_f32_16x16x32_bf16(qi1,  kr1f, si, 0,0,0);
            si = __builtin_amdgcn_mfma_f32_16x16x32_bf16(nqr0, ki0f, si, 0,0,0);
            si = __builtin_amdgcn_mfma_f32_16x16x32_bf16(nqr1, ki1f, si, 0,0,0);
            Sr[nb] = sr; Si[nb] = si;
        }

        // magnitude + online softmax (rows = quad*4 + r, spread over 16 lanes)
        float mag[4][4];
        float tmax[4] = {-1e30f, -1e30f, -1e30f, -1e30f};
#pragma unroll
        for (int nb = 0; nb < 4; ++nb)
#pragma unroll
            for (int r = 0; r < 4; ++r) {
                float a = Sr[nb][r], c = Si[nb][r];
                float mg = SCALE_ * sqrtf(a*a + c*c);
                mag[nb][r] = mg;
                tmax[r] = fmaxf(tmax[r], mg);
            }
#pragma unroll
        for (int off = 1; off < 16; off <<= 1)
#pragma unroll
            for (int r = 0; r < 4; ++r)
                tmax[r] = fmaxf(tmax[r], __shfl_xor(tmax[r], off));

        float alpha[4];
#pragma unroll
        for (int r = 0; r < 4; ++r) {
            float mn = fmaxf(m_[r], tmax[r]);
            alpha[r] = __expf(m_[r] - mn);
            m_[r] = mn;
        }
        float p[4][4];
        float tsum[4] = {0.f, 0.f, 0.f, 0.f};
#pragma unroll
        for (int nb = 0; nb < 4; ++nb)
#pragma unroll
            for (int r = 0; r < 4; ++r) {
                float pv = __expf(mag[nb][r] - m_[r]);
                p[nb][r] = pv;
                tsum[r] += pv;
            }
#pragma unroll
        for (int off = 1; off < 16; off <<= 1)
#pragma unroll
            for (int r = 0; r < 4; ++r)
                tsum[r] += __shfl_xor(tsum[r], off);
#pragma unroll
        for (int r = 0; r < 4; ++r) l_[r] = l_[r]*alpha[r] + tsum[r];
#pragma unroll
        for (int nb = 0; nb < 4; ++nb)
#pragma unroll
            for (int r = 0; r < 4; ++r) { Or[nb][r] *= alpha[r]; Oi[nb][r] *= alpha[r]; }

        // P: C-layout -> LDS -> A-layout
#pragma unroll
        for (int nb = 0; nb < 4; ++nb)
#pragma unroll
            for (int r = 0; r < 4; ++r)
                Ps[(w*16 + quad*4 + r)*72 + nb*16 + lc] = (bf16)p[nb][r];
        __syncthreads();

        bf16x8 p0 = *(bf16x8*)&Ps[frow + quad*8];
        bf16x8 p1 = *(bf16x8*)&Ps[frow + 32 + quad*8];
#pragma unroll
        for (int nb = 0; nb < 4; ++nb) {        // nb indexes hd chunks here
            int vrow = (nb*16 + lc)*72;
            bf16x8 v0 = *(bf16x8*)&Vr[vrow + quad*8];
            bf16x8 v1 = *(bf16x8*)&Vr[vrow + 32 + quad*8];
            Or[nb] = __builtin_amdgcn_mfma_f32_16x16x32_bf16(p0, v0, Or[nb], 0,0,0);
            Or[nb] = __builtin_amdgcn_mfma_f32_16x16x32_bf16(p1, v1, Or[nb], 0,0,0);
            v0 = *(bf16x8*)&Vi[vrow + quad*8];
            v1 = *(bf16x8*)&Vi[vrow + 32 + quad*8];
            Oi[nb] = __builtin_amdgcn_mfma_f32_16x16x32_bf16(p0, v0, Oi[nb], 0,0,0);
            Oi[nb] = __builtin_amdgcn_mfma_f32_16x16x32_bf16(p1, v1, Oi[nb], 0,0,0);
        }
        __syncthreads();
    }

    float inv[4];
#pragma unroll
    for (int r = 0; r < 4; ++r) inv[r] = 1.f / l_[r];
    bf16* obr = obuf + ((size_t)(0*BB_ + b)*NN_)*DIM_;
    bf16* obi = obuf + ((size_t)(1*BB_ + b)*NN_)*DIM_;
#pragma unroll
    for (int nb = 0; nb < 4; ++nb)
#pragma unroll
        for (int r = 0; r < 4; ++r) {
            int gn = q0 + w*16 + quad*4 + r;
            int gc = h*HD_ + nb*16 + lc;
            obr[(size_t)gn*DIM_ + gc] = (bf16)(Or[nb][r] * inv[r]);
            obi[(size_t)gn*DIM_ + gc] = (bf16)(Oi[nb][r] * inv[r]);
        }
}

// ---------------------------------------------------------------------------
// Output GEMM: out[m,c] = o[m,:] . Wout[c,:] + b[c];  M=4096, C=1024, K=1024
// A is bf16 (ws), W converted f32->bf16 in staging, f32 output.
// ---------------------------------------------------------------------------
__global__ __launch_bounds__(256) void out_gemm(
    const bf16* __restrict__ obuf,
    const float* __restrict__ Wr, const float* __restrict__ Wi,
    const float* __restrict__ br, const float* __restrict__ bi,
    float* __restrict__ out)
{
    const int z = blockIdx.z;
    const bf16*  __restrict__ A    = obuf + (size_t)z * MTOT_ * DIM_;
    const float* __restrict__ W    = z ? Wi : Wr;
    const float* __restrict__ bias = z ? bi : br;
    float* __restrict__ dst        = out + (size_t)z * MTOT_ * DIM_;
    const int n0 = blockIdx.x * 128;
    const int m0 = blockIdx.y * 128;

    __shared__ bf16 As[128*40];
    __shared__ bf16 Bs[128*40];

    const int tid  = threadIdx.x;
    const int w    = tid >> 6, lane = tid & 63;
    const int quad = lane >> 4, lc = lane & 15;
    const int wm   = (w >> 1) * 64, wn = (w & 1) * 64;

    const fx4 fzero = {0.f, 0.f, 0.f, 0.f};
    fx4 acc[4][4];
#pragma unroll
    for (int mi = 0; mi < 4; ++mi)
#pragma unroll
        for (int ni = 0; ni < 4; ++ni) acc[mi][ni] = fzero;

    for (int k0 = 0; k0 < DIM_; k0 += 32) {
#pragma unroll
        for (int it = 0; it < 2; ++it) {
            int flat = it*2048 + tid*8;
            int row = flat >> 5, col = flat & 31;
            *(bf16x8*)&As[row*40 + col] = *(const bf16x8*)(A + (size_t)(m0+row)*DIM_ + k0 + col);
            const float* pb = W + (size_t)(n0+row)*DIM_ + k0 + col;
            fx4 b0 = *(const fx4*)pb, b1 = *(const fx4*)(pb+4);
            bf16x8 bv;
#pragma unroll
            for (int j = 0; j < 4; ++j) { bv[j] = (bf16)b0[j]; bv[j+4] = (bf16)b1[j]; }
            *(bf16x8*)&Bs[row*40 + col] = bv;
        }
        __syncthreads();

        bf16x8 af[4], bfr[4];
#pragma unroll
        for (int mi = 0; mi < 4; ++mi) af[mi]  = *(bf16x8*)&As[(wm + mi*16 + lc)*40 + quad*8];
#pragma unroll
        for (int ni = 0; ni < 4; ++ni) bfr[ni] = *(bf16x8*)&Bs[(wn + ni*16 + lc)*40 + quad*8];
#pragma unroll
        for (int mi = 0; mi < 4; ++mi)
#pragma unroll
            for (int ni = 0; ni < 4; ++ni)
                acc[mi][ni] = __builtin_amdgcn_mfma_f32_16x16x32_bf16(af[mi], bfr[ni], acc[mi][ni], 0, 0, 0);
        __syncthreads();
    }

#pragma unroll
    for (int mi = 0; mi < 4; ++mi)
#pragma unroll
        for (int ni = 0; ni < 4; ++ni)
#pragma unroll
            for (int r = 0; r < 4; ++r) {
                int gm = m0 + wm + mi*16 + quad*4 + r;
                int gc = n0 + wn + ni*16 + lc;
                dst[(size_t)gm*DIM_ + gc] = acc[mi][ni][r] + bias[gc];
            }
}

// ---------------------------------------------------------------------------
extern "C" void kernel_launch(void* const* d_in, const int* in_sizes, int n_in,
                              void* d_out, int out_size, void* d_ws, size_t ws_size,
                              hipStream_t stream) {
    const float* xr  = (const float*)d_in[0];
    const float* xi  = (const float*)d_in[1];
    const float* Wqr = (const float*)d_in[2];
    const float* bqr = (const float*)d_in[3];
    const float* Wqi = (const float*)d_in[4];
    const float* bqi = (const float*)d_in[5];
    const float* Wor = (const float*)d_in[6];
    const float* bor = (const float*)d_in[7];
    const float* Woi = (const float*)d_in[8];
    const float* boi = (const float*)d_in[9];
    float* out = (float*)d_out;

    bf16* ws = (bf16*)d_ws;
    const size_t per = (size_t)2 * BB_ * HEADS_ * NN_ * HD_;   // 8388608 elems
    bf16* qbuf = ws;
    bf16* kbuf = ws + per;
    bf16* vbuf = ws + 2*per;
    bf16* obuf = ws + 3*per;   // 2*B*N*D = 8388608 elems

    qkv_gemm<<<dim3(24, 32, 2), 256, 0, stream>>>(xr, xi, Wqr, Wqi, bqr, bqi, qbuf, kbuf, vbuf);
    attn_fwd<<<dim3(NN_/64, HEADS_, BB_), 256, 0, stream>>>(qbuf, kbuf, vbuf, obuf);
    out_gemm<<<dim3(8, 32, 2), 256, 0, stream>>>(obuf, Wor, Woi, bor, boi, out);
}